// Round 12
// baseline (354.109 us; speedup 1.0000x reference)
//
#include <hip/hip_runtime.h>

#define N_NODES 100000
#define N_EDGES 1200000
#define N_GRAPHS 256
#define NBUCK 392            // buckets of 256 nodes: 392*256 = 100352 >= N
#define EBLK 98              // edge-pass blocks
#define EPB 12245            // ceil(E/98)
#define DCAP 4608            // max edges per bucket handled in LDS (mean 3072, sd 55)

typedef __attribute__((ext_vector_type(8))) short bf16x8;
typedef __attribute__((ext_vector_type(4))) float f32x4;

// ---- bf16 helpers (fp32 <-> bf16 as ushort, RNE) ----
__device__ inline unsigned short f2b(float f) {
    union { float f; unsigned u; } c; c.f = f;
    unsigned u = c.u;
    u += 0x7fff + ((u >> 16) & 1);
    return (unsigned short)(u >> 16);
}
__device__ inline float blo(unsigned u) { union { unsigned i; float f; } c; c.i = u << 16; return c.f; }
__device__ inline float bhi(unsigned u) { union { unsigned i; float f; } c; c.i = u & 0xffff0000u; return c.f; }
__device__ inline float b2f(unsigned short h) { union { unsigned i; float f; } c; c.i = ((unsigned)h) << 16; return c.f; }

// ---------------- bucket phase A: per-(bucket, block) histogram ----------------
__global__ __launch_bounds__(256) void bucketA(const int* __restrict__ ei, int* __restrict__ histm) {
    __shared__ int h[NBUCK];
    int k = blockIdx.x, tid = threadIdx.x;
    for (int t = tid; t < NBUCK; t += 256) h[t] = 0;
    __syncthreads();
    int e0 = k * EPB, e1 = min(e0 + EPB, N_EDGES);
    for (int e = e0 + tid; e < e1; e += 256) {
        int dd = ei[N_EDGES + e];
        atomicAdd(&h[dd >> 8], 1);
    }
    __syncthreads();
    for (int t = tid; t < NBUCK; t += 256) histm[t * EBLK + k] = h[t];
}

// ---------------- phase B: scan histm -> per-(bucket,block) start offsets + bucket starts ----------------
__global__ __launch_bounds__(512) void bucketB(int* __restrict__ histm, int* __restrict__ bstart) {
    __shared__ int sb[512];
    int tid = threadIdx.x;
    int tot = 0;
    if (tid < NBUCK) {
        for (int k = 0; k < EBLK; k++) tot += histm[tid * EBLK + k];
    }
    sb[tid] = tot;
    __syncthreads();
    int acc = tot;
    for (int off = 1; off < 512; off <<= 1) {
        int v = (tid >= off) ? sb[tid - off] : 0;
        __syncthreads();
        sb[tid] = acc = acc + v;
        __syncthreads();
    }
    int excl = acc - tot;
    if (tid < NBUCK) {
        bstart[tid] = excl;
        int run = excl;
        for (int k = 0; k < EBLK; k++) {
            int v = histm[tid * EBLK + k];
            histm[tid * EBLK + k] = run;
            run += v;
        }
    }
    if (tid == 0) bstart[NBUCK] = N_EDGES;
}

// ---------------- phase C: scatter packed (src<<8 | dstlow) into bucket-grouped ebuf ----------------
__global__ __launch_bounds__(256) void bucketC(const int* __restrict__ ei, const int* __restrict__ histm,
                                               int* __restrict__ ebuf) {
    __shared__ int cur[NBUCK];
    int k = blockIdx.x, tid = threadIdx.x;
    for (int t = tid; t < NBUCK; t += 256) cur[t] = histm[t * EBLK + k];
    __syncthreads();
    int e0 = k * EPB, e1 = min(e0 + EPB, N_EDGES);
    for (int e = e0 + tid; e < e1; e += 256) {
        int ss = ei[e];
        int dd = ei[N_EDGES + e];
        int pos = atomicAdd(&cur[dd >> 8], 1);
        ebuf[pos] = (ss << 8) | (dd & 255);
    }
}

// ---------------- phase D: per-bucket counting sort -> rowptr + esrc (coalesced writes) ----------------
__global__ __launch_bounds__(256) void bucketD(const int* __restrict__ ebuf, const int* __restrict__ bstart,
                                               int* __restrict__ rowptr, int* __restrict__ esrc) {
    __shared__ int ecache[DCAP];
    __shared__ int stage[DCAP];
    __shared__ int hist[256], off[256];
    int b = blockIdx.x, tid = threadIdx.x;
    int seg0 = bstart[b], seg1 = bstart[b + 1];
    int cnt = seg1 - seg0;
    hist[tid] = 0;
    int lim = min(cnt, DCAP);
    for (int i = tid; i < lim; i += 256) ecache[i] = ebuf[seg0 + i];
    __syncthreads();
    for (int i = tid; i < cnt; i += 256) {
        int p = (i < DCAP) ? ecache[i] : ebuf[seg0 + i];
        atomicAdd(&hist[p & 255], 1);
    }
    __syncthreads();
    int v = hist[tid];
    off[tid] = v;
    __syncthreads();
    int acc = v;
    for (int o = 1; o < 256; o <<= 1) {
        int t = (tid >= o) ? off[tid - o] : 0;
        __syncthreads();
        off[tid] = acc = acc + t;
        __syncthreads();
    }
    int excl = acc - v;
    rowptr[b * 256 + tid] = seg0 + excl;
    off[tid] = excl;
    __syncthreads();
    if (cnt <= DCAP) {
        for (int i = tid; i < cnt; i += 256) {
            int p = ecache[i];
            int pos = atomicAdd(&off[p & 255], 1);
            stage[pos] = (p >> 8) << 7;    // pre-scaled byte offset (bf16 64-dim row = 128 B)
        }
        __syncthreads();
        for (int i = tid; i < cnt; i += 256) esrc[seg0 + i] = stage[i];
    } else {                               // correctness fallback, never in practice
        for (int i = tid; i < cnt; i += 256) {
            int p = (i < DCAP) ? ecache[i] : ebuf[seg0 + i];
            int pos = atomicAdd(&off[p & 255], 1);
            esrc[seg0 + pos] = (p >> 8) << 7;
        }
    }
}

// ---------------- setup: xcast (blocks 0..390) + prepack (391..422) + zero A/B/cnt (423..551) ----------------
__global__ __launch_bounds__(256) void setup_kernel(const float* __restrict__ x, unsigned short* __restrict__ xb,
                                                    const float* __restrict__ W2l, const float* __restrict__ W2r,
                                                    unsigned short* __restrict__ pw2, float* __restrict__ zbase) {
    int blk = blockIdx.x, tid = threadIdx.x;
    if (blk < 391) {
        int n = blk * 256 + tid;
        if (n < N_NODES) {
            const float4* x4 = (const float4*)x;
            float4 v0 = x4[(size_t)n * 2], v1 = x4[(size_t)n * 2 + 1];
            uint4 p;
            p.x = (unsigned)f2b(v0.x) | ((unsigned)f2b(v0.y) << 16);
            p.y = (unsigned)f2b(v0.z) | ((unsigned)f2b(v0.w) << 16);
            p.z = (unsigned)f2b(v1.x) | ((unsigned)f2b(v1.y) << 16);
            p.w = (unsigned)f2b(v1.z) | ((unsigned)f2b(v1.w) << 16);
            ((uint4*)xb)[n] = p;
        }
    } else if (blk < 423) {
        int r = (blk - 391) * 256 + tid;   // 8192 total
        int j = r & 7, lane = (r >> 3) & 63, t = (r >> 9) & 3, s = (r >> 11) & 3;
        int k = s * 32 + (lane >> 4) * 8 + j;
        int n = t * 16 + (lane & 15);
        float v = (k < 64) ? W2l[k * 64 + n] : W2r[(k - 64) * 64 + n];
        pw2[r] = f2b(v);
    } else {
        int i = (blk - 423) * 256 + tid;   // 33024 floats: A(16384) B(16384) cnt(256)
        if (i < 33024) zbase[i] = 0.0f;
    }
}

// ---------------- layer 1: wave/node, 16 edges x 4 uint-lanes, 32 edges in flight ----------------
__global__ __launch_bounds__(256) void layer1_fused(const float* __restrict__ x, const unsigned short* __restrict__ xb,
                                                    const int* __restrict__ rowptr, const int* __restrict__ esrc,
                                                    const float* __restrict__ Wl, const float* __restrict__ b,
                                                    const float* __restrict__ Wr, unsigned short* __restrict__ ob) {
    __shared__ float sa[4][8], sx[4][8];
    int tid = threadIdx.x;
    int sub = tid >> 6, lane = tid & 63;
    int grp = lane >> 2, q = lane & 3;             // 16 edge-groups x 4 uint-lanes
    int n = blockIdx.x * 4 + sub;
    int r0 = __builtin_amdgcn_readfirstlane(rowptr[n]);
    int r1 = __builtin_amdgcn_readfirstlane(rowptr[n + 1]);
    const unsigned* xbu = (const unsigned*)xb;     // x row = 16 B = 4 uints
    float a0 = 0.f, a1 = 0.f;
#pragma unroll
    for (int c = 0; c < 2; c++) {                  // 32 edges in flight
        int idx = r0 + 16 * c + grp;
        if (idx < r1) {
            unsigned v = xbu[(esrc[idx] >> 5) + q];    // (src*128)>>5 = src*4
            a0 += blo(v); a1 += bhi(v);
        }
    }
    for (int e = r0 + 32; e < r1; e += 16) {       // rare tail (deg > 32)
        int idx = e + grp;
        if (idx < r1) {
            unsigned v = xbu[(esrc[idx] >> 5) + q];
            a0 += blo(v); a1 += bhi(v);
        }
    }
#pragma unroll
    for (int m = 4; m <= 32; m <<= 1) {
        a0 += __shfl_xor(a0, m);
        a1 += __shfl_xor(a1, m);
    }
    if (lane < 4) { sa[sub][2 * lane] = a0; sa[sub][2 * lane + 1] = a1; }
    if (lane >= 8 && lane < 16) sx[sub][lane - 8] = x[(size_t)n * 8 + (lane - 8)];
    __syncthreads();
    float invn = 1.0f / fmaxf((float)(r1 - r0), 1.0f);
    float al = 0.f, ar = 0.f;
#pragma unroll
    for (int kk = 0; kk < 8; kk++) {
        al += sa[sub][kk] * Wl[kk * 64 + lane];
        ar += sx[sub][kk] * Wr[kk * 64 + lane];
    }
    ob[(size_t)n * 64 + lane] = f2b(fmaxf(al * invn + b[lane] + ar, 0.0f));
}

// ---------------- fused layer 2: gather-mean (4 nodes/wave) + MFMA GEMM per 16-node tile ----------------
__global__ __launch_bounds__(256) void agg_gemm(const unsigned short* __restrict__ hb,
                                                const int* __restrict__ rowptr,
                                                const int* __restrict__ esrc,
                                                const unsigned short* __restrict__ pw,
                                                const float* __restrict__ bias,
                                                unsigned short* __restrict__ outb) {
    __shared__ unsigned short smean[16][64];       // 2 KB
    int tid = threadIdx.x;
    int sub = tid >> 6, lane = tid & 63;
    int grp = lane >> 3, q = lane & 7;
    int tile = blockIdx.x;                         // 6250 tiles of 16 nodes
    const uint4* h16 = (const uint4*)hb;
    for (int i = 0; i < 4; i++) {
        int n = tile * 16 + sub * 4 + i;
        int r0 = __builtin_amdgcn_readfirstlane(rowptr[n]);
        int r1 = __builtin_amdgcn_readfirstlane(rowptr[n + 1]);
        uint4 v[3];
#pragma unroll
        for (int c = 0; c < 3; c++) {
            uint4 vv; vv.x = 0u; vv.y = 0u; vv.z = 0u; vv.w = 0u;
            int idx = r0 + 8 * c + grp;
            if (idx < r1) vv = h16[(esrc[idx] >> 4) + q];
            v[c] = vv;
        }
        float a[8];
#pragma unroll
        for (int j = 0; j < 8; j++) a[j] = 0.f;
#pragma unroll
        for (int c = 0; c < 3; c++) {
            a[0] += blo(v[c].x); a[1] += bhi(v[c].x);
            a[2] += blo(v[c].y); a[3] += bhi(v[c].y);
            a[4] += blo(v[c].z); a[5] += bhi(v[c].z);
            a[6] += blo(v[c].w); a[7] += bhi(v[c].w);
        }
        for (int e = r0 + 24; e < r1; e += 8) {    // rare tail (deg > 24)
            int idx = e + grp;
            if (idx < r1) {
                uint4 vv = h16[(esrc[idx] >> 4) + q];
                a[0] += blo(vv.x); a[1] += bhi(vv.x);
                a[2] += blo(vv.y); a[3] += bhi(vv.y);
                a[4] += blo(vv.z); a[5] += bhi(vv.z);
                a[6] += blo(vv.w); a[7] += bhi(vv.w);
            }
        }
#pragma unroll
        for (int j = 0; j < 8; j++) {
            a[j] += __shfl_xor(a[j], 8);
            a[j] += __shfl_xor(a[j], 16);
            a[j] += __shfl_xor(a[j], 32);
        }
        if (grp == 0) {
            float invn = 1.0f / fmaxf((float)(r1 - r0), 1.0f);
#pragma unroll
            for (int j = 0; j < 8; j++) smean[sub * 4 + i][q * 8 + j] = f2b(a[j] * invn);
        }
    }
    __syncthreads();
    // MFMA phase: wave sub computes output cols [sub*16, sub*16+16)
    int col = lane & 15, quad = lane >> 4;
    int m = tile * 16 + col;
    union U { uint4 u; bf16x8 b; };
    U a0, a1, a2, a3;
    a0.u = *(const uint4*)&smean[col][quad * 8];        // k in [0,32)   (agg)
    a1.u = *(const uint4*)&smean[col][32 + quad * 8];   // k in [32,64)  (agg)
    const uint4* srow = (const uint4*)(hb + (size_t)m * 64);
    a2.u = srow[quad];                                  // k in [64,96)  (self)
    a3.u = srow[4 + quad];                              // k in [96,128) (self)
    const uint4* pwv = (const uint4*)pw;
    int t = sub;
    U b0, b1, b2, b3;
    b0.u = pwv[(0 * 4 + t) * 64 + lane];
    b1.u = pwv[(1 * 4 + t) * 64 + lane];
    b2.u = pwv[(2 * 4 + t) * 64 + lane];
    b3.u = pwv[(3 * 4 + t) * 64 + lane];
    f32x4 acc = {0.f, 0.f, 0.f, 0.f};
    acc = __builtin_amdgcn_mfma_f32_16x16x32_bf16(a0.b, b0.b, acc, 0, 0, 0);
    acc = __builtin_amdgcn_mfma_f32_16x16x32_bf16(a1.b, b1.b, acc, 0, 0, 0);
    acc = __builtin_amdgcn_mfma_f32_16x16x32_bf16(a2.b, b2.b, acc, 0, 0, 0);
    acc = __builtin_amdgcn_mfma_f32_16x16x32_bf16(a3.b, b3.b, acc, 0, 0, 0);
    float bi = bias[t * 16 + col];
#pragma unroll
    for (int i = 0; i < 4; i++) {                       // D: row = quad*4+i, col = lane&15
        int node = tile * 16 + quad * 4 + i;
        outb[(size_t)node * 64 + t * 16 + col] = f2b(fmaxf(acc[i] + bi, 0.0f));
    }
}

// ---------------- layer-3 gather + pooled A/B/cnt accumulate ----------------
__global__ __launch_bounds__(256) void aggpool3(const unsigned short* __restrict__ hb,
                                                const int* __restrict__ rowptr,
                                                const int* __restrict__ esrc,
                                                const int* __restrict__ batch,
                                                float* __restrict__ A, float* __restrict__ B,
                                                float* __restrict__ cntf) {
    __shared__ float sa[4][64], sbb[4][64];
    __shared__ int sbat[4];
    int tid = threadIdx.x;
    int sub = tid >> 6, lane = tid & 63;
    int grp = lane >> 3, q = lane & 7;
    int n = blockIdx.x * 4 + sub;
    int r0 = __builtin_amdgcn_readfirstlane(rowptr[n]);
    int r1 = __builtin_amdgcn_readfirstlane(rowptr[n + 1]);
    const uint4* h16 = (const uint4*)hb;
    float self = b2f(hb[(size_t)n * 64 + lane]);   // coalesced self row (for B pool)
    uint4 v[3];
#pragma unroll
    for (int c = 0; c < 3; c++) {
        uint4 vv; vv.x = 0u; vv.y = 0u; vv.z = 0u; vv.w = 0u;
        int idx = r0 + 8 * c + grp;
        if (idx < r1) vv = h16[(esrc[idx] >> 4) + q];
        v[c] = vv;
    }
    float a[8];
#pragma unroll
    for (int j = 0; j < 8; j++) a[j] = 0.f;
#pragma unroll
    for (int c = 0; c < 3; c++) {
        a[0] += blo(v[c].x); a[1] += bhi(v[c].x);
        a[2] += blo(v[c].y); a[3] += bhi(v[c].y);
        a[4] += blo(v[c].z); a[5] += bhi(v[c].z);
        a[6] += blo(v[c].w); a[7] += bhi(v[c].w);
    }
    for (int e = r0 + 24; e < r1; e += 8) {
        int idx = e + grp;
        if (idx < r1) {
            uint4 vv = h16[(esrc[idx] >> 4) + q];
            a[0] += blo(vv.x); a[1] += bhi(vv.x);
            a[2] += blo(vv.y); a[3] += bhi(vv.y);
            a[4] += blo(vv.z); a[5] += bhi(vv.z);
            a[6] += blo(vv.w); a[7] += bhi(vv.w);
        }
    }
#pragma unroll
    for (int j = 0; j < 8; j++) {
        a[j] += __shfl_xor(a[j], 8);
        a[j] += __shfl_xor(a[j], 16);
        a[j] += __shfl_xor(a[j], 32);
    }
    if (lane == 0) sbat[sub] = batch[n];
    sbb[sub][lane] = self;
    if (grp == 0) {
        float invn = 1.0f / fmaxf((float)(r1 - r0), 1.0f);
#pragma unroll
        for (int j = 0; j < 8; j++) sa[sub][q * 8 + j] = a[j] * invn;
    }
    __syncthreads();
    if (sub == 0) {                // sorted batch: block covers 1..4 graphs
        float accA = sa[0][lane], accB = sbb[0][lane];
        int cur = sbat[0], ac = 1;
#pragma unroll
        for (int i = 1; i < 4; i++) {
            int bi = sbat[i];
            if (bi != cur) {
                atomicAdd(&A[cur * 64 + lane], accA);
                atomicAdd(&B[cur * 64 + lane], accB);
                if (lane == 0) atomicAdd(&cntf[cur], (float)ac);
                cur = bi; accA = 0.f; accB = 0.f; ac = 0;
            }
            accA += sa[i][lane]; accB += sbb[i][lane]; ac++;
        }
        atomicAdd(&A[cur * 64 + lane], accA);
        atomicAdd(&B[cur * 64 + lane], accB);
        if (lane == 0) atomicAdd(&cntf[cur], (float)ac);
    }
}

// ---------------- head: g = A@W3l + cnt*b3 + B@W3r, then relu(g@Wc1+bc1)@Wc2+bc2 ----------------
__global__ __launch_bounds__(256) void head2_kernel(const float* __restrict__ A, const float* __restrict__ B,
                                                    const float* __restrict__ cntf,
                                                    const float* __restrict__ W3l, const float* __restrict__ b3,
                                                    const float* __restrict__ W3r,
                                                    const float* __restrict__ Wc1, const float* __restrict__ bc1,
                                                    const float* __restrict__ Wc2, const float* __restrict__ bc2,
                                                    float* __restrict__ out) {
    __shared__ float sA[4][64], sB[4][64], sh3[4][64];
    int tid = threadIdx.x, sub = tid >> 6, lane = tid & 63;
    int gid = blockIdx.x * 4 + sub;
    sA[sub][lane] = A[gid * 64 + lane];
    sB[sub][lane] = B[gid * 64 + lane];
    float cg = cntf[gid];
    __syncthreads();
    float v = cg * b3[lane];
#pragma unroll 8
    for (int k = 0; k < 64; k++) {
        v += sA[sub][k] * W3l[k * 64 + lane] + sB[sub][k] * W3r[k * 64 + lane];
    }
    sh3[sub][lane] = v;
    __syncthreads();
    int j = lane & 31, kh = lane >> 5;
    float a = 0.f;
#pragma unroll
    for (int kk = 0; kk < 32; kk++) {
        int k = kh * 32 + kk;
        a += sh3[sub][k] * Wc1[k * 32 + j];
    }
    a += __shfl_xor(a, 32);
    float contrib = (lane < 32) ? fmaxf(a + bc1[j], 0.0f) * Wc2[j] : 0.0f;
    contrib += __shfl_xor(contrib, 16);
    contrib += __shfl_xor(contrib, 8);
    contrib += __shfl_xor(contrib, 4);
    contrib += __shfl_xor(contrib, 2);
    contrib += __shfl_xor(contrib, 1);
    if (lane == 0) out[gid] = contrib + bc2[0];
}

extern "C" void kernel_launch(void* const* d_in, const int* in_sizes, int n_in,
                              void* d_out, int out_size, void* d_ws, size_t ws_size,
                              hipStream_t stream) {
    const float* x   = (const float*)d_in[0];
    const int*   ei  = (const int*)d_in[1];
    const int*   bat = (const int*)d_in[2];
    const float* W1l = (const float*)d_in[3];
    const float* b1  = (const float*)d_in[4];
    const float* W1r = (const float*)d_in[5];
    const float* W2l = (const float*)d_in[6];
    const float* b2  = (const float*)d_in[7];
    const float* W2r = (const float*)d_in[8];
    const float* W3l = (const float*)d_in[9];
    const float* b3  = (const float*)d_in[10];
    const float* W3r = (const float*)d_in[11];
    const float* Wc1 = (const float*)d_in[12];
    const float* bc1 = (const float*)d_in[13];
    const float* Wc2 = (const float*)d_in[14];
    const float* bc2 = (const float*)d_in[15];

    float* ws = (float*)d_ws;
    // ---- workspace layout (float offsets) ----
    int*    rowptr = (int*)(ws);                              // [0, 100352)
    int*    esrc   = (int*)(ws + 100352);                     // [100352, 1300480)
    float*  A      = ws + 1300480;                            // 16384
    float*  B      = ws + 1316864;                            // 16384
    float*  cntf   = ws + 1333248;                            // 256   (A,B,cnt contiguous: 33024)
    unsigned short* pw2 = (unsigned short*)(ws + 1333504);    // 8192 bf16
    unsigned short* xb  = (unsigned short*)(ws + 1337600);    // N*8 bf16
    unsigned short* hb1 = (unsigned short*)(ws + 1737728);    // N*64 bf16 = 3.2M floats
    unsigned short* hb2 = (unsigned short*)(ws + 4937728);
    int*    ebuf   = (int*)(ws + 8137728);                    // 1200000
    int*    histm  = (int*)(ws + 9337728);                    // 38416
    int*    bstart = (int*)(ws + 9376144);                    // 393

    bucketA<<<EBLK, 256, 0, stream>>>(ei, histm);
    bucketB<<<1, 512, 0, stream>>>(histm, bstart);
    bucketC<<<EBLK, 256, 0, stream>>>(ei, histm, ebuf);
    bucketD<<<NBUCK, 256, 0, stream>>>(ebuf, bstart, rowptr, esrc);
    setup_kernel<<<552, 256, 0, stream>>>(x, xb, W2l, W2r, pw2, A);

    layer1_fused<<<N_NODES / 4, 256, 0, stream>>>(x, xb, rowptr, esrc, W1l, b1, W1r, hb1);
    agg_gemm<<<N_NODES / 16, 256, 0, stream>>>(hb1, rowptr, esrc, pw2, b2, hb2);
    aggpool3<<<N_NODES / 4, 256, 0, stream>>>(hb2, rowptr, esrc, bat, A, B, cntf);

    head2_kernel<<<N_GRAPHS / 4, 256, 0, stream>>>(A, B, cntf, W3l, b3, W3r, Wc1, bc1, Wc2, bc2,
                                                   (float*)d_out);
}

// Round 13
// 313.235 us; speedup vs baseline: 1.1305x; 1.1305x over previous
//
#include <hip/hip_runtime.h>

#define N_NODES 100000
#define N_EDGES 1200000
#define N_GRAPHS 256
#define NBUCK 392            // buckets of 256 nodes: 392*256 = 100352 >= N
#define EBLK 98              // edge-pass blocks
#define EPB 12245            // ceil(E/98)
#define DCAP 4608            // max edges per bucket handled in LDS (mean 3072, sd 55)

typedef __attribute__((ext_vector_type(8))) short bf16x8;
typedef __attribute__((ext_vector_type(4))) float f32x4;

// ---- bf16 helpers (fp32 <-> bf16 as ushort, RNE) ----
__device__ inline unsigned short f2b(float f) {
    union { float f; unsigned u; } c; c.f = f;
    unsigned u = c.u;
    u += 0x7fff + ((u >> 16) & 1);
    return (unsigned short)(u >> 16);
}
__device__ inline float blo(unsigned u) { union { unsigned i; float f; } c; c.i = u << 16; return c.f; }
__device__ inline float bhi(unsigned u) { union { unsigned i; float f; } c; c.i = u & 0xffff0000u; return c.f; }
__device__ inline float b2f(unsigned short h) { union { unsigned i; float f; } c; c.i = ((unsigned)h) << 16; return c.f; }

// ---------------- bucket phase A: per-(bucket, block) histogram ----------------
__global__ __launch_bounds__(256) void bucketA(const int* __restrict__ ei, int* __restrict__ histm) {
    __shared__ int h[NBUCK];
    int k = blockIdx.x, tid = threadIdx.x;
    for (int t = tid; t < NBUCK; t += 256) h[t] = 0;
    __syncthreads();
    int e0 = k * EPB, e1 = min(e0 + EPB, N_EDGES);
    for (int e = e0 + tid; e < e1; e += 256) {
        int dd = ei[N_EDGES + e];
        atomicAdd(&h[dd >> 8], 1);
    }
    __syncthreads();
    for (int t = tid; t < NBUCK; t += 256) histm[t * EBLK + k] = h[t];
}

// ---------------- phase B: scan histm -> per-(bucket,block) start offsets + bucket starts ----------------
__global__ __launch_bounds__(512) void bucketB(int* __restrict__ histm, int* __restrict__ bstart) {
    __shared__ int sb[512];
    int tid = threadIdx.x;
    int tot = 0;
    if (tid < NBUCK) {
        for (int k = 0; k < EBLK; k++) tot += histm[tid * EBLK + k];
    }
    sb[tid] = tot;
    __syncthreads();
    int acc = tot;
    for (int off = 1; off < 512; off <<= 1) {
        int v = (tid >= off) ? sb[tid - off] : 0;
        __syncthreads();
        sb[tid] = acc = acc + v;
        __syncthreads();
    }
    int excl = acc - tot;
    if (tid < NBUCK) {
        bstart[tid] = excl;
        int run = excl;
        for (int k = 0; k < EBLK; k++) {
            int v = histm[tid * EBLK + k];
            histm[tid * EBLK + k] = run;
            run += v;
        }
    }
    if (tid == 0) bstart[NBUCK] = N_EDGES;
}

// ---------------- phase C: scatter packed (src<<8 | dstlow) into bucket-grouped ebuf ----------------
__global__ __launch_bounds__(256) void bucketC(const int* __restrict__ ei, const int* __restrict__ histm,
                                               int* __restrict__ ebuf) {
    __shared__ int cur[NBUCK];
    int k = blockIdx.x, tid = threadIdx.x;
    for (int t = tid; t < NBUCK; t += 256) cur[t] = histm[t * EBLK + k];
    __syncthreads();
    int e0 = k * EPB, e1 = min(e0 + EPB, N_EDGES);
    for (int e = e0 + tid; e < e1; e += 256) {
        int ss = ei[e];
        int dd = ei[N_EDGES + e];
        int pos = atomicAdd(&cur[dd >> 8], 1);
        ebuf[pos] = (ss << 8) | (dd & 255);
    }
}

// ---------------- phase D: per-bucket counting sort -> rowptr + esrc (coalesced writes) ----------------
__global__ __launch_bounds__(256) void bucketD(const int* __restrict__ ebuf, const int* __restrict__ bstart,
                                               int* __restrict__ rowptr, int* __restrict__ esrc) {
    __shared__ int ecache[DCAP];
    __shared__ int stage[DCAP];
    __shared__ int hist[256], off[256];
    int b = blockIdx.x, tid = threadIdx.x;
    int seg0 = bstart[b], seg1 = bstart[b + 1];
    int cnt = seg1 - seg0;
    hist[tid] = 0;
    int lim = min(cnt, DCAP);
    for (int i = tid; i < lim; i += 256) ecache[i] = ebuf[seg0 + i];
    __syncthreads();
    for (int i = tid; i < cnt; i += 256) {
        int p = (i < DCAP) ? ecache[i] : ebuf[seg0 + i];
        atomicAdd(&hist[p & 255], 1);
    }
    __syncthreads();
    int v = hist[tid];
    off[tid] = v;
    __syncthreads();
    int acc = v;
    for (int o = 1; o < 256; o <<= 1) {
        int t = (tid >= o) ? off[tid - o] : 0;
        __syncthreads();
        off[tid] = acc = acc + t;
        __syncthreads();
    }
    int excl = acc - v;
    rowptr[b * 256 + tid] = seg0 + excl;
    off[tid] = excl;
    __syncthreads();
    if (cnt <= DCAP) {
        for (int i = tid; i < cnt; i += 256) {
            int p = ecache[i];
            int pos = atomicAdd(&off[p & 255], 1);
            stage[pos] = (p >> 8) << 7;    // pre-scaled byte offset (bf16 64-dim row = 128 B)
        }
        __syncthreads();
        for (int i = tid; i < cnt; i += 256) esrc[seg0 + i] = stage[i];
    } else {                               // correctness fallback, never in practice
        for (int i = tid; i < cnt; i += 256) {
            int p = (i < DCAP) ? ecache[i] : ebuf[seg0 + i];
            int pos = atomicAdd(&off[p & 255], 1);
            esrc[seg0 + pos] = (p >> 8) << 7;
        }
    }
}

// ---------------- setup: xcast (blocks 0..390) + prepack (391..422) + zero A/B/cnt (423..551) ----------------
__global__ __launch_bounds__(256) void setup_kernel(const float* __restrict__ x, unsigned short* __restrict__ xb,
                                                    const float* __restrict__ W2l, const float* __restrict__ W2r,
                                                    unsigned short* __restrict__ pw2, float* __restrict__ zbase) {
    int blk = blockIdx.x, tid = threadIdx.x;
    if (blk < 391) {
        int n = blk * 256 + tid;
        if (n < N_NODES) {
            const float4* x4 = (const float4*)x;
            float4 v0 = x4[(size_t)n * 2], v1 = x4[(size_t)n * 2 + 1];
            uint4 p;
            p.x = (unsigned)f2b(v0.x) | ((unsigned)f2b(v0.y) << 16);
            p.y = (unsigned)f2b(v0.z) | ((unsigned)f2b(v0.w) << 16);
            p.z = (unsigned)f2b(v1.x) | ((unsigned)f2b(v1.y) << 16);
            p.w = (unsigned)f2b(v1.z) | ((unsigned)f2b(v1.w) << 16);
            ((uint4*)xb)[n] = p;
        }
    } else if (blk < 423) {
        int r = (blk - 391) * 256 + tid;   // 8192 total
        int j = r & 7, lane = (r >> 3) & 63, t = (r >> 9) & 3, s = (r >> 11) & 3;
        int k = s * 32 + (lane >> 4) * 8 + j;
        int n = t * 16 + (lane & 15);
        float v = (k < 64) ? W2l[k * 64 + n] : W2r[(k - 64) * 64 + n];
        pw2[r] = f2b(v);
    } else {
        int i = (blk - 423) * 256 + tid;   // 33024 floats: A(16384) B(16384) cnt(256)
        if (i < 33024) zbase[i] = 0.0f;
    }
}

// ---------------- layer 1: wave/node, 16 edges x 4 uint-lanes, 32 edges in flight ----------------
__global__ __launch_bounds__(256) void layer1_fused(const float* __restrict__ x, const unsigned short* __restrict__ xb,
                                                    const int* __restrict__ rowptr, const int* __restrict__ esrc,
                                                    const float* __restrict__ Wl, const float* __restrict__ b,
                                                    const float* __restrict__ Wr, unsigned short* __restrict__ ob) {
    __shared__ float sa[4][8], sx[4][8];
    int tid = threadIdx.x;
    int sub = tid >> 6, lane = tid & 63;
    int grp = lane >> 2, q = lane & 3;             // 16 edge-groups x 4 uint-lanes
    int n = blockIdx.x * 4 + sub;
    int r0 = __builtin_amdgcn_readfirstlane(rowptr[n]);
    int r1 = __builtin_amdgcn_readfirstlane(rowptr[n + 1]);
    const unsigned* xbu = (const unsigned*)xb;     // x row = 16 B = 4 uints
    float a0 = 0.f, a1 = 0.f;
#pragma unroll
    for (int c = 0; c < 2; c++) {                  // 32 edges in flight
        int idx = r0 + 16 * c + grp;
        if (idx < r1) {
            unsigned v = xbu[(esrc[idx] >> 5) + q];    // (src*128)>>5 = src*4
            a0 += blo(v); a1 += bhi(v);
        }
    }
    for (int e = r0 + 32; e < r1; e += 16) {       // rare tail (deg > 32)
        int idx = e + grp;
        if (idx < r1) {
            unsigned v = xbu[(esrc[idx] >> 5) + q];
            a0 += blo(v); a1 += bhi(v);
        }
    }
#pragma unroll
    for (int m = 4; m <= 32; m <<= 1) {
        a0 += __shfl_xor(a0, m);
        a1 += __shfl_xor(a1, m);
    }
    if (lane < 4) { sa[sub][2 * lane] = a0; sa[sub][2 * lane + 1] = a1; }
    if (lane >= 8 && lane < 16) sx[sub][lane - 8] = x[(size_t)n * 8 + (lane - 8)];
    __syncthreads();
    float invn = 1.0f / fmaxf((float)(r1 - r0), 1.0f);
    float al = 0.f, ar = 0.f;
#pragma unroll
    for (int kk = 0; kk < 8; kk++) {
        al += sa[sub][kk] * Wl[kk * 64 + lane];
        ar += sx[sub][kk] * Wr[kk * 64 + lane];
    }
    ob[(size_t)n * 64 + lane] = f2b(fmaxf(al * invn + b[lane] + ar, 0.0f));
}

// ---------------- fused layer 2: gather-mean (4 nodes/wave) + MFMA GEMM per 16-node tile ----------------
__global__ __launch_bounds__(256) void agg_gemm(const unsigned short* __restrict__ hb,
                                                const int* __restrict__ rowptr,
                                                const int* __restrict__ esrc,
                                                const unsigned short* __restrict__ pw,
                                                const float* __restrict__ bias,
                                                unsigned short* __restrict__ outb) {
    __shared__ unsigned short smean[16][64];       // 2 KB
    int tid = threadIdx.x;
    int sub = tid >> 6, lane = tid & 63;
    int grp = lane >> 3, q = lane & 7;
    int tile = blockIdx.x;                         // 6250 tiles of 16 nodes
    const uint4* h16 = (const uint4*)hb;
    for (int i = 0; i < 4; i++) {
        int n = tile * 16 + sub * 4 + i;
        int r0 = __builtin_amdgcn_readfirstlane(rowptr[n]);
        int r1 = __builtin_amdgcn_readfirstlane(rowptr[n + 1]);
        uint4 v[3];
#pragma unroll
        for (int c = 0; c < 3; c++) {
            uint4 vv; vv.x = 0u; vv.y = 0u; vv.z = 0u; vv.w = 0u;
            int idx = r0 + 8 * c + grp;
            if (idx < r1) vv = h16[(esrc[idx] >> 4) + q];
            v[c] = vv;
        }
        float a[8];
#pragma unroll
        for (int j = 0; j < 8; j++) a[j] = 0.f;
#pragma unroll
        for (int c = 0; c < 3; c++) {
            a[0] += blo(v[c].x); a[1] += bhi(v[c].x);
            a[2] += blo(v[c].y); a[3] += bhi(v[c].y);
            a[4] += blo(v[c].z); a[5] += bhi(v[c].z);
            a[6] += blo(v[c].w); a[7] += bhi(v[c].w);
        }
        for (int e = r0 + 24; e < r1; e += 8) {    // rare tail (deg > 24)
            int idx = e + grp;
            if (idx < r1) {
                uint4 vv = h16[(esrc[idx] >> 4) + q];
                a[0] += blo(vv.x); a[1] += bhi(vv.x);
                a[2] += blo(vv.y); a[3] += bhi(vv.y);
                a[4] += blo(vv.z); a[5] += bhi(vv.z);
                a[6] += blo(vv.w); a[7] += bhi(vv.w);
            }
        }
#pragma unroll
        for (int j = 0; j < 8; j++) {
            a[j] += __shfl_xor(a[j], 8);
            a[j] += __shfl_xor(a[j], 16);
            a[j] += __shfl_xor(a[j], 32);
        }
        if (grp == 0) {
            float invn = 1.0f / fmaxf((float)(r1 - r0), 1.0f);
#pragma unroll
            for (int j = 0; j < 8; j++) smean[sub * 4 + i][q * 8 + j] = f2b(a[j] * invn);
        }
    }
    __syncthreads();
    // MFMA phase: wave sub computes output cols [sub*16, sub*16+16)
    int col = lane & 15, quad = lane >> 4;
    int m = tile * 16 + col;
    union U { uint4 u; bf16x8 b; };
    U a0, a1, a2, a3;
    a0.u = *(const uint4*)&smean[col][quad * 8];        // k in [0,32)   (agg)
    a1.u = *(const uint4*)&smean[col][32 + quad * 8];   // k in [32,64)  (agg)
    const uint4* srow = (const uint4*)(hb + (size_t)m * 64);
    a2.u = srow[quad];                                  // k in [64,96)  (self)
    a3.u = srow[4 + quad];                              // k in [96,128) (self)
    const uint4* pwv = (const uint4*)pw;
    int t = sub;
    U b0, b1, b2, b3;
    b0.u = pwv[(0 * 4 + t) * 64 + lane];
    b1.u = pwv[(1 * 4 + t) * 64 + lane];
    b2.u = pwv[(2 * 4 + t) * 64 + lane];
    b3.u = pwv[(3 * 4 + t) * 64 + lane];
    f32x4 acc = {0.f, 0.f, 0.f, 0.f};
    acc = __builtin_amdgcn_mfma_f32_16x16x32_bf16(a0.b, b0.b, acc, 0, 0, 0);
    acc = __builtin_amdgcn_mfma_f32_16x16x32_bf16(a1.b, b1.b, acc, 0, 0, 0);
    acc = __builtin_amdgcn_mfma_f32_16x16x32_bf16(a2.b, b2.b, acc, 0, 0, 0);
    acc = __builtin_amdgcn_mfma_f32_16x16x32_bf16(a3.b, b3.b, acc, 0, 0, 0);
    float bi = bias[t * 16 + col];
#pragma unroll
    for (int i = 0; i < 4; i++) {                       // D: row = quad*4+i, col = lane&15
        int node = tile * 16 + quad * 4 + i;
        outb[(size_t)node * 64 + t * 16 + col] = f2b(fmaxf(acc[i] + bi, 0.0f));
    }
}

// ---------------- layer-3 gather + pooled A accumulate (R11-proven version) ----------------
__global__ __launch_bounds__(256) void aggpool3(const unsigned short* __restrict__ hb,
                                                const int* __restrict__ rowptr,
                                                const int* __restrict__ esrc,
                                                const int* __restrict__ batch, float* __restrict__ A) {
    __shared__ float sa[4][64];
    __shared__ int sbat[4];
    int tid = threadIdx.x;
    int sub = tid >> 6, lane = tid & 63;
    int grp = lane >> 3, q = lane & 7;
    int n = blockIdx.x * 4 + sub;
    int r0 = __builtin_amdgcn_readfirstlane(rowptr[n]);
    int r1 = __builtin_amdgcn_readfirstlane(rowptr[n + 1]);
    const uint4* h16 = (const uint4*)hb;
    uint4 v[3];
#pragma unroll
    for (int c = 0; c < 3; c++) {
        uint4 vv; vv.x = 0u; vv.y = 0u; vv.z = 0u; vv.w = 0u;
        int idx = r0 + 8 * c + grp;
        if (idx < r1) {
            int off = esrc[idx];
            vv = h16[(off >> 4) + q];
        }
        v[c] = vv;
    }
    float a[8];
#pragma unroll
    for (int j = 0; j < 8; j++) a[j] = 0.f;
#pragma unroll
    for (int c = 0; c < 3; c++) {
        a[0] += blo(v[c].x); a[1] += bhi(v[c].x);
        a[2] += blo(v[c].y); a[3] += bhi(v[c].y);
        a[4] += blo(v[c].z); a[5] += bhi(v[c].z);
        a[6] += blo(v[c].w); a[7] += bhi(v[c].w);
    }
    for (int e = r0 + 24; e < r1; e += 8) {
        int idx = e + grp;
        if (idx < r1) {
            int off = esrc[idx];
            uint4 vv = h16[(off >> 4) + q];
            a[0] += blo(vv.x); a[1] += bhi(vv.x);
            a[2] += blo(vv.y); a[3] += bhi(vv.y);
            a[4] += blo(vv.z); a[5] += bhi(vv.z);
            a[6] += blo(vv.w); a[7] += bhi(vv.w);
        }
    }
#pragma unroll
    for (int j = 0; j < 8; j++) {
        a[j] += __shfl_xor(a[j], 8);
        a[j] += __shfl_xor(a[j], 16);
        a[j] += __shfl_xor(a[j], 32);
    }
    if (lane == 0) sbat[sub] = batch[n];
    if (grp == 0) {
        float invn = 1.0f / fmaxf((float)(r1 - r0), 1.0f);
#pragma unroll
        for (int j = 0; j < 8; j++) sa[sub][q * 8 + j] = a[j] * invn;
    }
    __syncthreads();
    if (sub == 0) {                // sorted batch: block covers 1..4 graphs
        int b0 = sbat[0], b3v = sbat[3];
        if (b0 == b3v) {
            float s = sa[0][lane] + sa[1][lane] + sa[2][lane] + sa[3][lane];
            atomicAdd(&A[b0 * 64 + lane], s);
        } else {
            float acc = sa[0][lane]; int cur = b0;
#pragma unroll
            for (int i = 1; i < 4; i++) {
                int bi = sbat[i];
                if (bi != cur) { atomicAdd(&A[cur * 64 + lane], acc); cur = bi; acc = 0.f; }
                acc += sa[i][lane];
            }
            atomicAdd(&A[cur * 64 + lane], acc);
        }
    }
}

// ---------------- poolB: B[g] = sum h2 rows, cnt[g] = node count (sorted batch) ----------------
__global__ __launch_bounds__(256) void poolB_kernel(const unsigned short* __restrict__ hb,
                                                    const int* __restrict__ batch,
                                                    float* __restrict__ B, float* __restrict__ cntf) {
    int d = threadIdx.x & 63;
    int grp = threadIdx.x >> 6;
    int n0 = blockIdx.x * 256;
    int cur = -1; float acc = 0.f; int ac = 0;
    for (int i = grp; i < 256; i += 4) {
        int n = n0 + i;
        if (n >= N_NODES) break;
        int bb = batch[n];
        if (bb != cur) {
            if (cur >= 0) {
                atomicAdd(&B[cur * 64 + d], acc);
                if (d == 0) atomicAdd(&cntf[cur], (float)ac);
            }
            cur = bb; acc = 0.f; ac = 0;
        }
        acc += b2f(hb[(size_t)n * 64 + d]);
        ac++;
    }
    if (cur >= 0) {
        atomicAdd(&B[cur * 64 + d], acc);
        if (d == 0) atomicAdd(&cntf[cur], (float)ac);
    }
}

// ---------------- head: g = A@W3l + cnt*b3 + B@W3r, then relu(g@Wc1+bc1)@Wc2+bc2 ----------------
__global__ __launch_bounds__(256) void head2_kernel(const float* __restrict__ A, const float* __restrict__ B,
                                                    const float* __restrict__ cntf,
                                                    const float* __restrict__ W3l, const float* __restrict__ b3,
                                                    const float* __restrict__ W3r,
                                                    const float* __restrict__ Wc1, const float* __restrict__ bc1,
                                                    const float* __restrict__ Wc2, const float* __restrict__ bc2,
                                                    float* __restrict__ out) {
    __shared__ float sA[4][64], sB[4][64], sh3[4][64];
    int tid = threadIdx.x, sub = tid >> 6, lane = tid & 63;
    int gid = blockIdx.x * 4 + sub;
    sA[sub][lane] = A[gid * 64 + lane];
    sB[sub][lane] = B[gid * 64 + lane];
    float cg = cntf[gid];
    __syncthreads();
    float v = cg * b3[lane];
#pragma unroll 8
    for (int k = 0; k < 64; k++) {
        v += sA[sub][k] * W3l[k * 64 + lane] + sB[sub][k] * W3r[k * 64 + lane];
    }
    sh3[sub][lane] = v;
    __syncthreads();
    int j = lane & 31, kh = lane >> 5;
    float a = 0.f;
#pragma unroll
    for (int kk = 0; kk < 32; kk++) {
        int k = kh * 32 + kk;
        a += sh3[sub][k] * Wc1[k * 32 + j];
    }
    a += __shfl_xor(a, 32);
    float contrib = (lane < 32) ? fmaxf(a + bc1[j], 0.0f) * Wc2[j] : 0.0f;
    contrib += __shfl_xor(contrib, 16);
    contrib += __shfl_xor(contrib, 8);
    contrib += __shfl_xor(contrib, 4);
    contrib += __shfl_xor(contrib, 2);
    contrib += __shfl_xor(contrib, 1);
    if (lane == 0) out[gid] = contrib + bc2[0];
}

extern "C" void kernel_launch(void* const* d_in, const int* in_sizes, int n_in,
                              void* d_out, int out_size, void* d_ws, size_t ws_size,
                              hipStream_t stream) {
    const float* x   = (const float*)d_in[0];
    const int*   ei  = (const int*)d_in[1];
    const int*   bat = (const int*)d_in[2];
    const float* W1l = (const float*)d_in[3];
    const float* b1  = (const float*)d_in[4];
    const float* W1r = (const float*)d_in[5];
    const float* W2l = (const float*)d_in[6];
    const float* b2  = (const float*)d_in[7];
    const float* W2r = (const float*)d_in[8];
    const float* W3l = (const float*)d_in[9];
    const float* b3  = (const float*)d_in[10];
    const float* W3r = (const float*)d_in[11];
    const float* Wc1 = (const float*)d_in[12];
    const float* bc1 = (const float*)d_in[13];
    const float* Wc2 = (const float*)d_in[14];
    const float* bc2 = (const float*)d_in[15];

    float* ws = (float*)d_ws;
    // ---- workspace layout (float offsets) ----
    int*    rowptr = (int*)(ws);                              // [0, 100352)
    int*    esrc   = (int*)(ws + 100352);                     // [100352, 1300480)
    float*  A      = ws + 1300480;                            // 16384
    float*  B      = ws + 1316864;                            // 16384
    float*  cntf   = ws + 1333248;                            // 256   (A,B,cnt contiguous: 33024)
    unsigned short* pw2 = (unsigned short*)(ws + 1333504);    // 8192 bf16
    unsigned short* xb  = (unsigned short*)(ws + 1337600);    // N*8 bf16
    unsigned short* hb1 = (unsigned short*)(ws + 1737728);    // N*64 bf16 = 3.2M floats
    unsigned short* hb2 = (unsigned short*)(ws + 4937728);
    int*    ebuf   = (int*)(ws + 8137728);                    // 1200000
    int*    histm  = (int*)(ws + 9337728);                    // 38416
    int*    bstart = (int*)(ws + 9376144);                    // 393

    bucketA<<<EBLK, 256, 0, stream>>>(ei, histm);
    bucketB<<<1, 512, 0, stream>>>(histm, bstart);
    bucketC<<<EBLK, 256, 0, stream>>>(ei, histm, ebuf);
    bucketD<<<NBUCK, 256, 0, stream>>>(ebuf, bstart, rowptr, esrc);
    setup_kernel<<<552, 256, 0, stream>>>(x, xb, W2l, W2r, pw2, A);

    layer1_fused<<<N_NODES / 4, 256, 0, stream>>>(x, xb, rowptr, esrc, W1l, b1, W1r, hb1);
    agg_gemm<<<N_NODES / 16, 256, 0, stream>>>(hb1, rowptr, esrc, pw2, b2, hb2);
    aggpool3<<<N_NODES / 4, 256, 0, stream>>>(hb2, rowptr, esrc, bat, A);
    poolB_kernel<<<(N_NODES + 255) / 256, 256, 0, stream>>>(hb2, bat, B, cntf);

    head2_kernel<<<N_GRAPHS / 4, 256, 0, stream>>>(A, B, cntf, W3l, b3, W3r, Wc1, bc1, Wc2, bc2,
                                                   (float*)d_out);
}

// Round 14
// 274.249 us; speedup vs baseline: 1.2912x; 1.1422x over previous
//
#include <hip/hip_runtime.h>

#define N_NODES 100000
#define N_EDGES 1200000
#define N_GRAPHS 256
#define NBUCK 392            // buckets of 256 nodes: 392*256 = 100352 >= N
#define EBLK 98              // edge-pass blocks
#define EPB 12245            // ceil(E/98)
#define DCAP 4608            // max edges per bucket handled in LDS (mean 3072, sd 55)

typedef __attribute__((ext_vector_type(8))) short bf16x8;
typedef __attribute__((ext_vector_type(4))) float f32x4;

// ---- bf16 helpers (fp32 <-> bf16 as ushort, RNE) ----
__device__ inline unsigned short f2b(float f) {
    union { float f; unsigned u; } c; c.f = f;
    unsigned u = c.u;
    u += 0x7fff + ((u >> 16) & 1);
    return (unsigned short)(u >> 16);
}
__device__ inline float blo(unsigned u) { union { unsigned i; float f; } c; c.i = u << 16; return c.f; }
__device__ inline float bhi(unsigned u) { union { unsigned i; float f; } c; c.i = u & 0xffff0000u; return c.f; }
__device__ inline float b2f(unsigned short h) { union { unsigned i; float f; } c; c.i = ((unsigned)h) << 16; return c.f; }

// ---------------- setup: xcast + prepack + zero A/B + bucketA histogram ----------------
// blocks 0..390: xcast | 391..422: prepack | 423..550: zero A,B | 551..648: bucketA
__global__ __launch_bounds__(256) void setup_kernel(const float* __restrict__ x, unsigned short* __restrict__ xb,
                                                    const float* __restrict__ W2l, const float* __restrict__ W2r,
                                                    unsigned short* __restrict__ pw2, float* __restrict__ zbase,
                                                    const int* __restrict__ ei, int* __restrict__ histm) {
    __shared__ int h[NBUCK];
    int blk = blockIdx.x, tid = threadIdx.x;
    if (blk < 391) {
        int n = blk * 256 + tid;
        if (n < N_NODES) {
            const float4* x4 = (const float4*)x;
            float4 v0 = x4[(size_t)n * 2], v1 = x4[(size_t)n * 2 + 1];
            uint4 p;
            p.x = (unsigned)f2b(v0.x) | ((unsigned)f2b(v0.y) << 16);
            p.y = (unsigned)f2b(v0.z) | ((unsigned)f2b(v0.w) << 16);
            p.z = (unsigned)f2b(v1.x) | ((unsigned)f2b(v1.y) << 16);
            p.w = (unsigned)f2b(v1.z) | ((unsigned)f2b(v1.w) << 16);
            ((uint4*)xb)[n] = p;
        }
    } else if (blk < 423) {
        int r = (blk - 391) * 256 + tid;   // 8192 total
        int j = r & 7, lane = (r >> 3) & 63, t = (r >> 9) & 3, s = (r >> 11) & 3;
        int k = s * 32 + (lane >> 4) * 8 + j;
        int n = t * 16 + (lane & 15);
        float v = (k < 64) ? W2l[k * 64 + n] : W2r[(k - 64) * 64 + n];
        pw2[r] = f2b(v);
    } else if (blk < 551) {
        int i = (blk - 423) * 256 + tid;   // 32768 floats: A(16384) B(16384)
        zbase[i] = 0.0f;
    } else {
        int k = blk - 551;                 // bucketA, transposed histm (coalesced)
        for (int t = tid; t < NBUCK; t += 256) h[t] = 0;
        __syncthreads();
        int e0 = k * EPB, e1 = min(e0 + EPB, N_EDGES);
        for (int e = e0 + tid; e < e1; e += 256) {
            int dd = ei[N_EDGES + e];
            atomicAdd(&h[dd >> 8], 1);
        }
        __syncthreads();
        for (int t = tid; t < NBUCK; t += 256) histm[k * NBUCK + t] = h[t];
    }
}

// ---------------- phase B: scan histm (transposed, coalesced) -> offsets + bucket starts ----------------
__global__ __launch_bounds__(512) void bucketB(int* __restrict__ histm, int* __restrict__ bstart) {
    __shared__ int sb[512];
    int tid = threadIdx.x;
    int tot = 0;
    if (tid < NBUCK) {
        for (int k = 0; k < EBLK; k++) tot += histm[k * NBUCK + tid];   // coalesced across tid
    }
    sb[tid] = tot;
    __syncthreads();
    int acc = tot;
    for (int off = 1; off < 512; off <<= 1) {
        int v = (tid >= off) ? sb[tid - off] : 0;
        __syncthreads();
        sb[tid] = acc = acc + v;
        __syncthreads();
    }
    int excl = acc - tot;
    if (tid < NBUCK) {
        bstart[tid] = excl;
        int run = excl;
        for (int k = 0; k < EBLK; k++) {
            int v = histm[k * NBUCK + tid];
            histm[k * NBUCK + tid] = run;
            run += v;
        }
    }
    if (tid == 0) bstart[NBUCK] = N_EDGES;
}

// ---------------- phase C: scatter packed (src<<8 | dstlow) into bucket-grouped ebuf ----------------
__global__ __launch_bounds__(256) void bucketC(const int* __restrict__ ei, const int* __restrict__ histm,
                                               int* __restrict__ ebuf) {
    __shared__ int cur[NBUCK];
    int k = blockIdx.x, tid = threadIdx.x;
    for (int t = tid; t < NBUCK; t += 256) cur[t] = histm[k * NBUCK + t];   // coalesced
    __syncthreads();
    int e0 = k * EPB, e1 = min(e0 + EPB, N_EDGES);
    for (int e = e0 + tid; e < e1; e += 256) {
        int ss = ei[e];
        int dd = ei[N_EDGES + e];
        int pos = atomicAdd(&cur[dd >> 8], 1);
        ebuf[pos] = (ss << 8) | (dd & 255);
    }
}

// ---------------- phase D: per-bucket counting sort -> rowptr + esrc (coalesced writes) ----------------
__global__ __launch_bounds__(256) void bucketD(const int* __restrict__ ebuf, const int* __restrict__ bstart,
                                               int* __restrict__ rowptr, int* __restrict__ esrc) {
    __shared__ int ecache[DCAP];
    __shared__ int stage[DCAP];
    __shared__ int hist[256], off[256];
    int b = blockIdx.x, tid = threadIdx.x;
    int seg0 = bstart[b], seg1 = bstart[b + 1];
    int cnt = seg1 - seg0;
    hist[tid] = 0;
    int lim = min(cnt, DCAP);
    for (int i = tid; i < lim; i += 256) ecache[i] = ebuf[seg0 + i];
    __syncthreads();
    for (int i = tid; i < cnt; i += 256) {
        int p = (i < DCAP) ? ecache[i] : ebuf[seg0 + i];
        atomicAdd(&hist[p & 255], 1);
    }
    __syncthreads();
    int v = hist[tid];
    off[tid] = v;
    __syncthreads();
    int acc = v;
    for (int o = 1; o < 256; o <<= 1) {
        int t = (tid >= o) ? off[tid - o] : 0;
        __syncthreads();
        off[tid] = acc = acc + t;
        __syncthreads();
    }
    int excl = acc - v;
    rowptr[b * 256 + tid] = seg0 + excl;
    off[tid] = excl;
    __syncthreads();
    if (cnt <= DCAP) {
        for (int i = tid; i < cnt; i += 256) {
            int p = ecache[i];
            int pos = atomicAdd(&off[p & 255], 1);
            stage[pos] = (p >> 8) << 7;    // pre-scaled byte offset (bf16 64-dim row = 128 B)
        }
        __syncthreads();
        for (int i = tid; i < cnt; i += 256) esrc[seg0 + i] = stage[i];
    } else {                               // correctness fallback, never in practice
        for (int i = tid; i < cnt; i += 256) {
            int p = (i < DCAP) ? ecache[i] : ebuf[seg0 + i];
            int pos = atomicAdd(&off[p & 255], 1);
            esrc[seg0 + pos] = (p >> 8) << 7;
        }
    }
}

// ---------------- layer 1: wave/node, 16 edges x 4 uint-lanes, 32 edges in flight ----------------
__global__ __launch_bounds__(256) void layer1_fused(const float* __restrict__ x, const unsigned short* __restrict__ xb,
                                                    const int* __restrict__ rowptr, const int* __restrict__ esrc,
                                                    const float* __restrict__ Wl, const float* __restrict__ b,
                                                    const float* __restrict__ Wr, unsigned short* __restrict__ ob) {
    __shared__ float sa[4][8], sx[4][8];
    int tid = threadIdx.x;
    int sub = tid >> 6, lane = tid & 63;
    int grp = lane >> 2, q = lane & 3;             // 16 edge-groups x 4 uint-lanes
    int n = blockIdx.x * 4 + sub;
    int r0 = __builtin_amdgcn_readfirstlane(rowptr[n]);
    int r1 = __builtin_amdgcn_readfirstlane(rowptr[n + 1]);
    const unsigned* xbu = (const unsigned*)xb;     // x row = 16 B = 4 uints
    float a0 = 0.f, a1 = 0.f;
#pragma unroll
    for (int c = 0; c < 2; c++) {                  // 32 edges in flight
        int idx = r0 + 16 * c + grp;
        if (idx < r1) {
            unsigned v = xbu[(esrc[idx] >> 5) + q];    // (src*128)>>5 = src*4
            a0 += blo(v); a1 += bhi(v);
        }
    }
    for (int e = r0 + 32; e < r1; e += 16) {       // rare tail (deg > 32)
        int idx = e + grp;
        if (idx < r1) {
            unsigned v = xbu[(esrc[idx] >> 5) + q];
            a0 += blo(v); a1 += bhi(v);
        }
    }
#pragma unroll
    for (int m = 4; m <= 32; m <<= 1) {
        a0 += __shfl_xor(a0, m);
        a1 += __shfl_xor(a1, m);
    }
    if (lane < 4) { sa[sub][2 * lane] = a0; sa[sub][2 * lane + 1] = a1; }
    if (lane >= 8 && lane < 16) sx[sub][lane - 8] = x[(size_t)n * 8 + (lane - 8)];
    __syncthreads();
    float invn = 1.0f / fmaxf((float)(r1 - r0), 1.0f);
    float al = 0.f, ar = 0.f;
#pragma unroll
    for (int kk = 0; kk < 8; kk++) {
        al += sa[sub][kk] * Wl[kk * 64 + lane];
        ar += sx[sub][kk] * Wr[kk * 64 + lane];
    }
    ob[(size_t)n * 64 + lane] = f2b(fmaxf(al * invn + b[lane] + ar, 0.0f));
}

// ---------------- fused layer 2: gather-mean + MFMA GEMM + B-pool epilogue ----------------
__global__ __launch_bounds__(256) void agg_gemm(const unsigned short* __restrict__ hb,
                                                const int* __restrict__ rowptr,
                                                const int* __restrict__ esrc,
                                                const unsigned short* __restrict__ pw,
                                                const float* __restrict__ bias,
                                                unsigned short* __restrict__ outb,
                                                const int* __restrict__ batch, float* __restrict__ B) {
    __shared__ unsigned short smean[16][64];       // 2 KB
    __shared__ int sbat16[16];
    int tid = threadIdx.x;
    int sub = tid >> 6, lane = tid & 63;
    int grp = lane >> 3, q = lane & 7;
    int tile = blockIdx.x;                         // 6250 tiles of 16 nodes
    const uint4* h16 = (const uint4*)hb;
    if (tid < 16) sbat16[tid] = batch[tile * 16 + tid];
    for (int i = 0; i < 4; i++) {
        int n = tile * 16 + sub * 4 + i;
        int r0 = __builtin_amdgcn_readfirstlane(rowptr[n]);
        int r1 = __builtin_amdgcn_readfirstlane(rowptr[n + 1]);
        uint4 v[3];
#pragma unroll
        for (int c = 0; c < 3; c++) {
            uint4 vv; vv.x = 0u; vv.y = 0u; vv.z = 0u; vv.w = 0u;
            int idx = r0 + 8 * c + grp;
            if (idx < r1) vv = h16[(esrc[idx] >> 4) + q];
            v[c] = vv;
        }
        float a[8];
#pragma unroll
        for (int j = 0; j < 8; j++) a[j] = 0.f;
#pragma unroll
        for (int c = 0; c < 3; c++) {
            a[0] += blo(v[c].x); a[1] += bhi(v[c].x);
            a[2] += blo(v[c].y); a[3] += bhi(v[c].y);
            a[4] += blo(v[c].z); a[5] += bhi(v[c].z);
            a[6] += blo(v[c].w); a[7] += bhi(v[c].w);
        }
        for (int e = r0 + 24; e < r1; e += 8) {    // rare tail (deg > 24)
            int idx = e + grp;
            if (idx < r1) {
                uint4 vv = h16[(esrc[idx] >> 4) + q];
                a[0] += blo(vv.x); a[1] += bhi(vv.x);
                a[2] += blo(vv.y); a[3] += bhi(vv.y);
                a[4] += blo(vv.z); a[5] += bhi(vv.z);
                a[6] += blo(vv.w); a[7] += bhi(vv.w);
            }
        }
#pragma unroll
        for (int j = 0; j < 8; j++) {
            a[j] += __shfl_xor(a[j], 8);
            a[j] += __shfl_xor(a[j], 16);
            a[j] += __shfl_xor(a[j], 32);
        }
        if (grp == 0) {
            float invn = 1.0f / fmaxf((float)(r1 - r0), 1.0f);
#pragma unroll
            for (int j = 0; j < 8; j++) smean[sub * 4 + i][q * 8 + j] = f2b(a[j] * invn);
        }
    }
    __syncthreads();
    // MFMA phase: wave sub computes output cols [sub*16, sub*16+16)
    int col = lane & 15, quad = lane >> 4;
    int m = tile * 16 + col;
    union U { uint4 u; bf16x8 b; };
    U a0, a1, a2, a3;
    a0.u = *(const uint4*)&smean[col][quad * 8];        // k in [0,32)   (agg)
    a1.u = *(const uint4*)&smean[col][32 + quad * 8];   // k in [32,64)  (agg)
    const uint4* srow = (const uint4*)(hb + (size_t)m * 64);
    a2.u = srow[quad];                                  // k in [64,96)  (self)
    a3.u = srow[4 + quad];                              // k in [96,128) (self)
    const uint4* pwv = (const uint4*)pw;
    int t = sub;
    U b0, b1, b2, b3;
    b0.u = pwv[(0 * 4 + t) * 64 + lane];
    b1.u = pwv[(1 * 4 + t) * 64 + lane];
    b2.u = pwv[(2 * 4 + t) * 64 + lane];
    b3.u = pwv[(3 * 4 + t) * 64 + lane];
    f32x4 acc = {0.f, 0.f, 0.f, 0.f};
    acc = __builtin_amdgcn_mfma_f32_16x16x32_bf16(a0.b, b0.b, acc, 0, 0, 0);
    acc = __builtin_amdgcn_mfma_f32_16x16x32_bf16(a1.b, b1.b, acc, 0, 0, 0);
    acc = __builtin_amdgcn_mfma_f32_16x16x32_bf16(a2.b, b2.b, acc, 0, 0, 0);
    acc = __builtin_amdgcn_mfma_f32_16x16x32_bf16(a3.b, b3.b, acc, 0, 0, 0);
    float bi = bias[t * 16 + col];
    float v[4];
#pragma unroll
    for (int i = 0; i < 4; i++) {                       // D: row = quad*4+i, col = lane&15
        int node = tile * 16 + quad * 4 + i;
        v[i] = fmaxf(acc[i] + bi, 0.0f);
        outb[(size_t)node * 64 + t * 16 + col] = f2b(v[i]);
    }
    // ---- B-pool epilogue (sorted batch; 96% of tiles are single-graph) ----
    int g0 = sbat16[0], g15 = sbat16[15];
    if (g0 == g15) {
        float s = (v[0] + v[1]) + (v[2] + v[3]);
        s += __shfl_xor(s, 16);
        s += __shfl_xor(s, 32);            // sum over 4 quads -> 16-node total per col
        if (quad == 0) atomicAdd(&B[g0 * 64 + t * 16 + col], s);
    } else {
        float accp = 0.f; int cur = sbat16[quad * 4];
#pragma unroll
        for (int i = 0; i < 4; i++) {
            int gi = sbat16[quad * 4 + i];
            if (gi != cur) { atomicAdd(&B[cur * 64 + t * 16 + col], accp); cur = gi; accp = 0.f; }
            accp += v[i];
        }
        atomicAdd(&B[cur * 64 + t * 16 + col], accp);
    }
}

// ---------------- layer-3 gather + pooled A accumulate (R11-proven version) ----------------
__global__ __launch_bounds__(256) void aggpool3(const unsigned short* __restrict__ hb,
                                                const int* __restrict__ rowptr,
                                                const int* __restrict__ esrc,
                                                const int* __restrict__ batch, float* __restrict__ A) {
    __shared__ float sa[4][64];
    __shared__ int sbat[4];
    int tid = threadIdx.x;
    int sub = tid >> 6, lane = tid & 63;
    int grp = lane >> 3, q = lane & 7;
    int n = blockIdx.x * 4 + sub;
    int r0 = __builtin_amdgcn_readfirstlane(rowptr[n]);
    int r1 = __builtin_amdgcn_readfirstlane(rowptr[n + 1]);
    const uint4* h16 = (const uint4*)hb;
    uint4 v[3];
#pragma unroll
    for (int c = 0; c < 3; c++) {
        uint4 vv; vv.x = 0u; vv.y = 0u; vv.z = 0u; vv.w = 0u;
        int idx = r0 + 8 * c + grp;
        if (idx < r1) {
            int off = esrc[idx];
            vv = h16[(off >> 4) + q];
        }
        v[c] = vv;
    }
    float a[8];
#pragma unroll
    for (int j = 0; j < 8; j++) a[j] = 0.f;
#pragma unroll
    for (int c = 0; c < 3; c++) {
        a[0] += blo(v[c].x); a[1] += bhi(v[c].x);
        a[2] += blo(v[c].y); a[3] += bhi(v[c].y);
        a[4] += blo(v[c].z); a[5] += bhi(v[c].z);
        a[6] += blo(v[c].w); a[7] += bhi(v[c].w);
    }
    for (int e = r0 + 24; e < r1; e += 8) {
        int idx = e + grp;
        if (idx < r1) {
            int off = esrc[idx];
            uint4 vv = h16[(off >> 4) + q];
            a[0] += blo(vv.x); a[1] += bhi(vv.x);
            a[2] += blo(vv.y); a[3] += bhi(vv.y);
            a[4] += blo(vv.z); a[5] += bhi(vv.z);
            a[6] += blo(vv.w); a[7] += bhi(vv.w);
        }
    }
#pragma unroll
    for (int j = 0; j < 8; j++) {
        a[j] += __shfl_xor(a[j], 8);
        a[j] += __shfl_xor(a[j], 16);
        a[j] += __shfl_xor(a[j], 32);
    }
    if (lane == 0) sbat[sub] = batch[n];
    if (grp == 0) {
        float invn = 1.0f / fmaxf((float)(r1 - r0), 1.0f);
#pragma unroll
        for (int j = 0; j < 8; j++) sa[sub][q * 8 + j] = a[j] * invn;
    }
    __syncthreads();
    if (sub == 0) {                // sorted batch: block covers 1..4 graphs
        int b0 = sbat[0], b3v = sbat[3];
        if (b0 == b3v) {
            float s = sa[0][lane] + sa[1][lane] + sa[2][lane] + sa[3][lane];
            atomicAdd(&A[b0 * 64 + lane], s);
        } else {
            float acc = sa[0][lane]; int cur = b0;
#pragma unroll
            for (int i = 1; i < 4; i++) {
                int bi = sbat[i];
                if (bi != cur) { atomicAdd(&A[cur * 64 + lane], acc); cur = bi; acc = 0.f; }
                acc += sa[i][lane];
            }
            atomicAdd(&A[cur * 64 + lane], acc);
        }
    }
}

// ---------------- head: cnt by binary search; g = A@W3l + cnt*b3 + B@W3r; MLP ----------------
__global__ __launch_bounds__(256) void head2_kernel(const float* __restrict__ A, const float* __restrict__ B,
                                                    const int* __restrict__ batch,
                                                    const float* __restrict__ W3l, const float* __restrict__ b3,
                                                    const float* __restrict__ W3r,
                                                    const float* __restrict__ Wc1, const float* __restrict__ bc1,
                                                    const float* __restrict__ Wc2, const float* __restrict__ bc2,
                                                    float* __restrict__ out) {
    __shared__ float sA[4][64], sB[4][64], sh3[4][64];
    __shared__ float scnt[4];
    int tid = threadIdx.x, sub = tid >> 6, lane = tid & 63;
    int gid = blockIdx.x * 4 + sub;
    sA[sub][lane] = A[gid * 64 + lane];
    sB[sub][lane] = B[gid * 64 + lane];
    if (lane == 0) {                       // cnt[gid] via binary search over sorted batch
        int lo = 0, hi = N_NODES;
        while (lo < hi) { int mid = (lo + hi) >> 1; if (batch[mid] < gid) lo = mid + 1; else hi = mid; }
        int lo2 = lo, hi2 = N_NODES;
        while (lo2 < hi2) { int mid = (lo2 + hi2) >> 1; if (batch[mid] < gid + 1) lo2 = mid + 1; else hi2 = mid; }
        scnt[sub] = (float)(lo2 - lo);
    }
    __syncthreads();
    float cg = scnt[sub];
    float v = cg * b3[lane];
#pragma unroll 8
    for (int k = 0; k < 64; k++) {
        v += sA[sub][k] * W3l[k * 64 + lane] + sB[sub][k] * W3r[k * 64 + lane];
    }
    sh3[sub][lane] = v;
    __syncthreads();
    int j = lane & 31, kh = lane >> 5;
    float a = 0.f;
#pragma unroll
    for (int kk = 0; kk < 32; kk++) {
        int k = kh * 32 + kk;
        a += sh3[sub][k] * Wc1[k * 32 + j];
    }
    a += __shfl_xor(a, 32);
    float contrib = (lane < 32) ? fmaxf(a + bc1[j], 0.0f) * Wc2[j] : 0.0f;
    contrib += __shfl_xor(contrib, 16);
    contrib += __shfl_xor(contrib, 8);
    contrib += __shfl_xor(contrib, 4);
    contrib += __shfl_xor(contrib, 2);
    contrib += __shfl_xor(contrib, 1);
    if (lane == 0) out[gid] = contrib + bc2[0];
}

extern "C" void kernel_launch(void* const* d_in, const int* in_sizes, int n_in,
                              void* d_out, int out_size, void* d_ws, size_t ws_size,
                              hipStream_t stream) {
    const float* x   = (const float*)d_in[0];
    const int*   ei  = (const int*)d_in[1];
    const int*   bat = (const int*)d_in[2];
    const float* W1l = (const float*)d_in[3];
    const float* b1  = (const float*)d_in[4];
    const float* W1r = (const float*)d_in[5];
    const float* W2l = (const float*)d_in[6];
    const float* b2  = (const float*)d_in[7];
    const float* W2r = (const float*)d_in[8];
    const float* W3l = (const float*)d_in[9];
    const float* b3  = (const float*)d_in[10];
    const float* W3r = (const float*)d_in[11];
    const float* Wc1 = (const float*)d_in[12];
    const float* bc1 = (const float*)d_in[13];
    const float* Wc2 = (const float*)d_in[14];
    const float* bc2 = (const float*)d_in[15];

    float* ws = (float*)d_ws;
    // ---- workspace layout (float offsets) ----
    int*    rowptr = (int*)(ws);                              // [0, 100352)
    int*    esrc   = (int*)(ws + 100352);                     // [100352, 1300480)
    float*  A      = ws + 1300480;                            // 16384
    float*  B      = ws + 1316864;                            // 16384  (A,B contiguous: 32768)
    unsigned short* pw2 = (unsigned short*)(ws + 1333504);    // 8192 bf16
    unsigned short* xb  = (unsigned short*)(ws + 1337600);    // N*8 bf16
    unsigned short* hb1 = (unsigned short*)(ws + 1737728);    // N*64 bf16 = 3.2M floats
    unsigned short* hb2 = (unsigned short*)(ws + 4937728);
    int*    ebuf   = (int*)(ws + 8137728);                    // 1200000
    int*    histm  = (int*)(ws + 9337728);                    // 98*392 = 38416 (transposed layout)
    int*    bstart = (int*)(ws + 9376144);                    // 393

    setup_kernel<<<649, 256, 0, stream>>>(x, xb, W2l, W2r, pw2, A, ei, histm);
    bucketB<<<1, 512, 0, stream>>>(histm, bstart);
    bucketC<<<EBLK, 256, 0, stream>>>(ei, histm, ebuf);
    bucketD<<<NBUCK, 256, 0, stream>>>(ebuf, bstart, rowptr, esrc);

    layer1_fused<<<N_NODES / 4, 256, 0, stream>>>(x, xb, rowptr, esrc, W1l, b1, W1r, hb1);
    agg_gemm<<<N_NODES / 16, 256, 0, stream>>>(hb1, rowptr, esrc, pw2, b2, hb2, bat, B);
    aggpool3<<<N_NODES / 4, 256, 0, stream>>>(hb2, rowptr, esrc, bat, A);

    head2_kernel<<<N_GRAPHS / 4, 256, 0, stream>>>(A, B, bat, W3l, b3, W3r, Wc1, bc1, Wc2, bc2,
                                                   (float*)d_out);
}

// Round 15
// 256.596 us; speedup vs baseline: 1.3800x; 1.0688x over previous
//
#include <hip/hip_runtime.h>

#define N_NODES 100000
#define N_EDGES 1200000
#define N_GRAPHS 256
#define NBUCK 392            // buckets of 256 nodes: 392*256 = 100352 >= N
#define EBLK 98              // edge-pass blocks
#define EPB 12245            // ceil(E/98)
#define DCAP 4608            // max edges per bucket handled in LDS (mean 3072, sd 55)

typedef __attribute__((ext_vector_type(8))) short bf16x8;
typedef __attribute__((ext_vector_type(4))) float f32x4;

// ---- bf16 helpers (fp32 <-> bf16 as ushort, RNE) ----
__device__ inline unsigned short f2b(float f) {
    union { float f; unsigned u; } c; c.f = f;
    unsigned u = c.u;
    u += 0x7fff + ((u >> 16) & 1);
    return (unsigned short)(u >> 16);
}
__device__ inline float blo(unsigned u) { union { unsigned i; float f; } c; c.i = u << 16; return c.f; }
__device__ inline float bhi(unsigned u) { union { unsigned i; float f; } c; c.i = u & 0xffff0000u; return c.f; }
__device__ inline float b2f(unsigned short h) { union { unsigned i; float f; } c; c.i = ((unsigned)h) << 16; return c.f; }

// ---------------- setup: xcast + prepack + zero A/B + bucketA histogram ----------------
// blocks 0..390: xcast | 391..422: prepack | 423..550: zero A,B | 551..648: bucketA
__global__ __launch_bounds__(256) void setup_kernel(const float* __restrict__ x, unsigned short* __restrict__ xb,
                                                    const float* __restrict__ W2l, const float* __restrict__ W2r,
                                                    unsigned short* __restrict__ pw2, float* __restrict__ zbase,
                                                    const int* __restrict__ ei, int* __restrict__ histm) {
    __shared__ int h[NBUCK];
    int blk = blockIdx.x, tid = threadIdx.x;
    if (blk < 391) {
        int n = blk * 256 + tid;
        if (n < N_NODES) {
            const float4* x4 = (const float4*)x;
            float4 v0 = x4[(size_t)n * 2], v1 = x4[(size_t)n * 2 + 1];
            uint4 p;
            p.x = (unsigned)f2b(v0.x) | ((unsigned)f2b(v0.y) << 16);
            p.y = (unsigned)f2b(v0.z) | ((unsigned)f2b(v0.w) << 16);
            p.z = (unsigned)f2b(v1.x) | ((unsigned)f2b(v1.y) << 16);
            p.w = (unsigned)f2b(v1.z) | ((unsigned)f2b(v1.w) << 16);
            ((uint4*)xb)[n] = p;
        }
    } else if (blk < 423) {
        int r = (blk - 391) * 256 + tid;   // 8192 total
        int j = r & 7, lane = (r >> 3) & 63, t = (r >> 9) & 3, s = (r >> 11) & 3;
        int k = s * 32 + (lane >> 4) * 8 + j;
        int n = t * 16 + (lane & 15);
        float v = (k < 64) ? W2l[k * 64 + n] : W2r[(k - 64) * 64 + n];
        pw2[r] = f2b(v);
    } else if (blk < 551) {
        int i = (blk - 423) * 256 + tid;   // 32768 floats: A(16384) B(16384)
        zbase[i] = 0.0f;
    } else {
        int k = blk - 551;                 // bucketA, transposed histm (coalesced)
        for (int t = tid; t < NBUCK; t += 256) h[t] = 0;
        __syncthreads();
        int e0 = k * EPB, e1 = min(e0 + EPB, N_EDGES);
        for (int e = e0 + tid; e < e1; e += 256) {
            int dd = ei[N_EDGES + e];
            atomicAdd(&h[dd >> 8], 1);
        }
        __syncthreads();
        for (int t = tid; t < NBUCK; t += 256) histm[k * NBUCK + t] = h[t];
    }
}

// ---------------- bucketC (with integrated scan): scatter packed edges into bucket-grouped ebuf ----------------
__global__ __launch_bounds__(512) void bucketC(const int* __restrict__ ei, const int* __restrict__ histm,
                                               int* __restrict__ ebuf, int* __restrict__ bstart) {
    __shared__ int sb[512];
    __shared__ int cur[NBUCK];
    int k = blockIdx.x, tid = threadIdx.x;
    int tot = 0;
    if (tid < NBUCK) {
        for (int kk = 0; kk < EBLK; kk++) tot += histm[kk * NBUCK + tid];   // coalesced
    }
    sb[tid] = tot;
    __syncthreads();
    int acc = tot;
    for (int off = 1; off < 512; off <<= 1) {
        int v = (tid >= off) ? sb[tid - off] : 0;
        __syncthreads();
        sb[tid] = acc = acc + v;
        __syncthreads();
    }
    int excl = acc - tot;              // exclusive bucket prefix
    if (tid < NBUCK) {
        if (k == 0) bstart[tid] = excl;
        int run = excl;
        for (int kk = 0; kk < k; kk++) run += histm[kk * NBUCK + tid];     // coalesced
        cur[tid] = run;
    }
    if (k == 0 && tid == 0) bstart[NBUCK] = N_EDGES;
    __syncthreads();
    int e0 = k * EPB, e1 = min(e0 + EPB, N_EDGES);
    for (int e = e0 + tid; e < e1; e += 512) {
        int ss = ei[e];
        int dd = ei[N_EDGES + e];
        int pos = atomicAdd(&cur[dd >> 8], 1);
        ebuf[pos] = (ss << 8) | (dd & 255);
    }
}

// ---------------- bucketD + fused layer-1: counting sort -> rowptr/esrc, then h1 from LDS srcs ----------------
__global__ __launch_bounds__(256) void bucketD_l1(const int* __restrict__ ebuf, const int* __restrict__ bstart,
                                                  int* __restrict__ rowptr, int* __restrict__ esrc,
                                                  const unsigned short* __restrict__ xb,
                                                  const float* __restrict__ W1l, const float* __restrict__ b1v,
                                                  const float* __restrict__ W1r, unsigned short* __restrict__ hb1) {
    __shared__ int ecache[DCAP];
    __shared__ int stage[DCAP];
    __shared__ int hist[256], off[256];
    __shared__ float smean[256][8];
    __shared__ unsigned short sxb[2048];       // 256 nodes x 8 bf16
    __shared__ float w1l[512], w1r[512], sb1[64];
    int b = blockIdx.x, tid = threadIdx.x;
    int seg0 = bstart[b], seg1 = bstart[b + 1];
    int cnt = seg1 - seg0;
    hist[tid] = 0;
    // independent aux loads
    int gn = b * 256 + tid;
    {
        uint4 z; z.x = 0u; z.y = 0u; z.z = 0u; z.w = 0u;
        ((uint4*)sxb)[tid] = (gn < N_NODES) ? ((const uint4*)xb)[gn] : z;  // contiguous rows
    }
    for (int i = tid; i < 512; i += 256) { w1l[i] = W1l[i]; w1r[i] = W1r[i]; }
    if (tid < 64) sb1[tid] = b1v[tid];
    int lim = min(cnt, DCAP);
    for (int i = tid; i < lim; i += 256) ecache[i] = ebuf[seg0 + i];
    __syncthreads();
    for (int i = tid; i < cnt; i += 256) {
        int p = (i < DCAP) ? ecache[i] : ebuf[seg0 + i];
        atomicAdd(&hist[p & 255], 1);
    }
    __syncthreads();
    int v = hist[tid];
    off[tid] = v;
    __syncthreads();
    int acc = v;
    for (int o = 1; o < 256; o <<= 1) {
        int t = (tid >= o) ? off[tid - o] : 0;
        __syncthreads();
        off[tid] = acc = acc + t;
        __syncthreads();
    }
    int excl = acc - v;
    rowptr[b * 256 + tid] = seg0 + excl;
    off[tid] = excl;
    __syncthreads();
    bool fits = (cnt <= DCAP);
    if (fits) {
        for (int i = tid; i < cnt; i += 256) {
            int p = ecache[i];
            int pos = atomicAdd(&off[p & 255], 1);
            stage[pos] = (p >> 8) << 7;    // pre-scaled byte offset (bf16 64-dim row = 128 B)
        }
        __syncthreads();
        for (int i = tid; i < cnt; i += 256) esrc[seg0 + i] = stage[i];
    } else {                               // correctness fallback, never in practice
        for (int i = tid; i < cnt; i += 256) {
            int p = (i < DCAP) ? ecache[i] : ebuf[seg0 + i];
            int pos = atomicAdd(&off[p & 255], 1);
            esrc[seg0 + pos] = (p >> 8) << 7;
        }
    }
    __syncthreads();
    // ---- fused layer-1: per-thread gather of this node's srcs (xb is L2-resident, 1.6 MB) ----
    const uint4* xb16 = (const uint4*)xb;
    float a0 = 0.f, a1 = 0.f, a2 = 0.f, a3 = 0.f, a4 = 0.f, a5 = 0.f, a6 = 0.f, a7 = 0.f;
    for (int i = 0; i < v; i++) {
        int so = fits ? stage[excl + i] : esrc[seg0 + excl + i];
        uint4 vv = xb16[so >> 7];
        a0 += blo(vv.x); a1 += bhi(vv.x);
        a2 += blo(vv.y); a3 += bhi(vv.y);
        a4 += blo(vv.z); a5 += bhi(vv.z);
        a6 += blo(vv.w); a7 += bhi(vv.w);
    }
    float invn = 1.0f / fmaxf((float)v, 1.0f);
    smean[tid][0] = a0 * invn; smean[tid][1] = a1 * invn;
    smean[tid][2] = a2 * invn; smean[tid][3] = a3 * invn;
    smean[tid][4] = a4 * invn; smean[tid][5] = a5 * invn;
    smean[tid][6] = a6 * invn; smean[tid][7] = a7 * invn;
    __syncthreads();
    // ---- epilogue: h1[n][d] = relu(mean@W1l + b1 + x@W1r), 4 nodes x 64 dims per pass ----
    int d = tid & 63, nq = tid >> 6;
#pragma unroll 4
    for (int p = 0; p < 64; p++) {
        int ln = p * 4 + nq;
        int n = b * 256 + ln;
        if (n < N_NODES) {
            float al = 0.f, ar = 0.f;
#pragma unroll
            for (int k = 0; k < 8; k++) {
                al += smean[ln][k] * w1l[k * 64 + d];
                ar += b2f(sxb[ln * 8 + k]) * w1r[k * 64 + d];
            }
            hb1[(size_t)n * 64 + d] = f2b(fmaxf(al + sb1[d] + ar, 0.0f));
        }
    }
}

// ---------------- fused layer 2: gather-mean + MFMA GEMM + B-pool epilogue ----------------
__global__ __launch_bounds__(256) void agg_gemm(const unsigned short* __restrict__ hb,
                                                const int* __restrict__ rowptr,
                                                const int* __restrict__ esrc,
                                                const unsigned short* __restrict__ pw,
                                                const float* __restrict__ bias,
                                                unsigned short* __restrict__ outb,
                                                const int* __restrict__ batch, float* __restrict__ B) {
    __shared__ unsigned short smean[16][64];       // 2 KB
    __shared__ int sbat16[16];
    int tid = threadIdx.x;
    int sub = tid >> 6, lane = tid & 63;
    int grp = lane >> 3, q = lane & 7;
    int tile = blockIdx.x;                         // 6250 tiles of 16 nodes
    const uint4* h16 = (const uint4*)hb;
    if (tid < 16) sbat16[tid] = batch[tile * 16 + tid];
    for (int i = 0; i < 4; i++) {
        int n = tile * 16 + sub * 4 + i;
        int r0 = __builtin_amdgcn_readfirstlane(rowptr[n]);
        int r1 = __builtin_amdgcn_readfirstlane(rowptr[n + 1]);
        uint4 v[3];
#pragma unroll
        for (int c = 0; c < 3; c++) {
            uint4 vv; vv.x = 0u; vv.y = 0u; vv.z = 0u; vv.w = 0u;
            int idx = r0 + 8 * c + grp;
            if (idx < r1) vv = h16[(esrc[idx] >> 4) + q];
            v[c] = vv;
        }
        float a[8];
#pragma unroll
        for (int j = 0; j < 8; j++) a[j] = 0.f;
#pragma unroll
        for (int c = 0; c < 3; c++) {
            a[0] += blo(v[c].x); a[1] += bhi(v[c].x);
            a[2] += blo(v[c].y); a[3] += bhi(v[c].y);
            a[4] += blo(v[c].z); a[5] += bhi(v[c].z);
            a[6] += blo(v[c].w); a[7] += bhi(v[c].w);
        }
        for (int e = r0 + 24; e < r1; e += 8) {    // rare tail (deg > 24)
            int idx = e + grp;
            if (idx < r1) {
                uint4 vv = h16[(esrc[idx] >> 4) + q];
                a[0] += blo(vv.x); a[1] += bhi(vv.x);
                a[2] += blo(vv.y); a[3] += bhi(vv.y);
                a[4] += blo(vv.z); a[5] += bhi(vv.z);
                a[6] += blo(vv.w); a[7] += bhi(vv.w);
            }
        }
#pragma unroll
        for (int j = 0; j < 8; j++) {
            a[j] += __shfl_xor(a[j], 8);
            a[j] += __shfl_xor(a[j], 16);
            a[j] += __shfl_xor(a[j], 32);
        }
        if (grp == 0) {
            float invn = 1.0f / fmaxf((float)(r1 - r0), 1.0f);
#pragma unroll
            for (int j = 0; j < 8; j++) smean[sub * 4 + i][q * 8 + j] = f2b(a[j] * invn);
        }
    }
    __syncthreads();
    // MFMA phase: wave sub computes output cols [sub*16, sub*16+16)
    int col = lane & 15, quad = lane >> 4;
    int m = tile * 16 + col;
    union U { uint4 u; bf16x8 b; };
    U a0, a1, a2, a3;
    a0.u = *(const uint4*)&smean[col][quad * 8];        // k in [0,32)   (agg)
    a1.u = *(const uint4*)&smean[col][32 + quad * 8];   // k in [32,64)  (agg)
    const uint4* srow = (const uint4*)(hb + (size_t)m * 64);
    a2.u = srow[quad];                                  // k in [64,96)  (self)
    a3.u = srow[4 + quad];                              // k in [96,128) (self)
    const uint4* pwv = (const uint4*)pw;
    int t = sub;
    U b0, b1, b2, b3;
    b0.u = pwv[(0 * 4 + t) * 64 + lane];
    b1.u = pwv[(1 * 4 + t) * 64 + lane];
    b2.u = pwv[(2 * 4 + t) * 64 + lane];
    b3.u = pwv[(3 * 4 + t) * 64 + lane];
    f32x4 acc = {0.f, 0.f, 0.f, 0.f};
    acc = __builtin_amdgcn_mfma_f32_16x16x32_bf16(a0.b, b0.b, acc, 0, 0, 0);
    acc = __builtin_amdgcn_mfma_f32_16x16x32_bf16(a1.b, b1.b, acc, 0, 0, 0);
    acc = __builtin_amdgcn_mfma_f32_16x16x32_bf16(a2.b, b2.b, acc, 0, 0, 0);
    acc = __builtin_amdgcn_mfma_f32_16x16x32_bf16(a3.b, b3.b, acc, 0, 0, 0);
    float bi = bias[t * 16 + col];
    float v[4];
#pragma unroll
    for (int i = 0; i < 4; i++) {                       // D: row = quad*4+i, col = lane&15
        int node = tile * 16 + quad * 4 + i;
        v[i] = fmaxf(acc[i] + bi, 0.0f);
        outb[(size_t)node * 64 + t * 16 + col] = f2b(v[i]);
    }
    // ---- B-pool epilogue (sorted batch; 96% of tiles are single-graph) ----
    int g0 = sbat16[0], g15 = sbat16[15];
    if (g0 == g15) {
        float s = (v[0] + v[1]) + (v[2] + v[3]);
        s += __shfl_xor(s, 16);
        s += __shfl_xor(s, 32);            // sum over 4 quads -> 16-node total per col
        if (quad == 0) atomicAdd(&B[g0 * 64 + t * 16 + col], s);
    } else {
        float accp = 0.f; int cur = sbat16[quad * 4];
#pragma unroll
        for (int i = 0; i < 4; i++) {
            int gi = sbat16[quad * 4 + i];
            if (gi != cur) { atomicAdd(&B[cur * 64 + t * 16 + col], accp); cur = gi; accp = 0.f; }
            accp += v[i];
        }
        atomicAdd(&B[cur * 64 + t * 16 + col], accp);
    }
}

// ---------------- layer-3 gather + pooled A accumulate (R11-proven version) ----------------
__global__ __launch_bounds__(256) void aggpool3(const unsigned short* __restrict__ hb,
                                                const int* __restrict__ rowptr,
                                                const int* __restrict__ esrc,
                                                const int* __restrict__ batch, float* __restrict__ A) {
    __shared__ float sa[4][64];
    __shared__ int sbat[4];
    int tid = threadIdx.x;
    int sub = tid >> 6, lane = tid & 63;
    int grp = lane >> 3, q = lane & 7;
    int n = blockIdx.x * 4 + sub;
    int r0 = __builtin_amdgcn_readfirstlane(rowptr[n]);
    int r1 = __builtin_amdgcn_readfirstlane(rowptr[n + 1]);
    const uint4* h16 = (const uint4*)hb;
    uint4 v[3];
#pragma unroll
    for (int c = 0; c < 3; c++) {
        uint4 vv; vv.x = 0u; vv.y = 0u; vv.z = 0u; vv.w = 0u;
        int idx = r0 + 8 * c + grp;
        if (idx < r1) {
            int off = esrc[idx];
            vv = h16[(off >> 4) + q];
        }
        v[c] = vv;
    }
    float a[8];
#pragma unroll
    for (int j = 0; j < 8; j++) a[j] = 0.f;
#pragma unroll
    for (int c = 0; c < 3; c++) {
        a[0] += blo(v[c].x); a[1] += bhi(v[c].x);
        a[2] += blo(v[c].y); a[3] += bhi(v[c].y);
        a[4] += blo(v[c].z); a[5] += bhi(v[c].z);
        a[6] += blo(v[c].w); a[7] += bhi(v[c].w);
    }
    for (int e = r0 + 24; e < r1; e += 8) {
        int idx = e + grp;
        if (idx < r1) {
            int off = esrc[idx];
            uint4 vv = h16[(off >> 4) + q];
            a[0] += blo(vv.x); a[1] += bhi(vv.x);
            a[2] += blo(vv.y); a[3] += bhi(vv.y);
            a[4] += blo(vv.z); a[5] += bhi(vv.z);
            a[6] += blo(vv.w); a[7] += bhi(vv.w);
        }
    }
#pragma unroll
    for (int j = 0; j < 8; j++) {
        a[j] += __shfl_xor(a[j], 8);
        a[j] += __shfl_xor(a[j], 16);
        a[j] += __shfl_xor(a[j], 32);
    }
    if (lane == 0) sbat[sub] = batch[n];
    if (grp == 0) {
        float invn = 1.0f / fmaxf((float)(r1 - r0), 1.0f);
#pragma unroll
        for (int j = 0; j < 8; j++) sa[sub][q * 8 + j] = a[j] * invn;
    }
    __syncthreads();
    if (sub == 0) {                // sorted batch: block covers 1..4 graphs
        int b0 = sbat[0], b3v = sbat[3];
        if (b0 == b3v) {
            float s = sa[0][lane] + sa[1][lane] + sa[2][lane] + sa[3][lane];
            atomicAdd(&A[b0 * 64 + lane], s);
        } else {
            float acc = sa[0][lane]; int cur = b0;
#pragma unroll
            for (int i = 1; i < 4; i++) {
                int bi = sbat[i];
                if (bi != cur) { atomicAdd(&A[cur * 64 + lane], acc); cur = bi; acc = 0.f; }
                acc += sa[i][lane];
            }
            atomicAdd(&A[cur * 64 + lane], acc);
        }
    }
}

// ---------------- head: cnt by binary search; g = A@W3l + cnt*b3 + B@W3r; MLP ----------------
__global__ __launch_bounds__(256) void head2_kernel(const float* __restrict__ A, const float* __restrict__ B,
                                                    const int* __restrict__ batch,
                                                    const float* __restrict__ W3l, const float* __restrict__ b3,
                                                    const float* __restrict__ W3r,
                                                    const float* __restrict__ Wc1, const float* __restrict__ bc1,
                                                    const float* __restrict__ Wc2, const float* __restrict__ bc2,
                                                    float* __restrict__ out) {
    __shared__ float sA[4][64], sB[4][64], sh3[4][64];
    __shared__ float scnt[4];
    int tid = threadIdx.x, sub = tid >> 6, lane = tid & 63;
    int gid = blockIdx.x * 4 + sub;
    sA[sub][lane] = A[gid * 64 + lane];
    sB[sub][lane] = B[gid * 64 + lane];
    if (lane == 0) {                       // cnt[gid] via binary search over sorted batch
        int lo = 0, hi = N_NODES;
        while (lo < hi) { int mid = (lo + hi) >> 1; if (batch[mid] < gid) lo = mid + 1; else hi = mid; }
        int lo2 = lo, hi2 = N_NODES;
        while (lo2 < hi2) { int mid = (lo2 + hi2) >> 1; if (batch[mid] < gid + 1) lo2 = mid + 1; else hi2 = mid; }
        scnt[sub] = (float)(lo2 - lo);
    }
    __syncthreads();
    float cg = scnt[sub];
    float v = cg * b3[lane];
#pragma unroll 8
    for (int k = 0; k < 64; k++) {
        v += sA[sub][k] * W3l[k * 64 + lane] + sB[sub][k] * W3r[k * 64 + lane];
    }
    sh3[sub][lane] = v;
    __syncthreads();
    int j = lane & 31, kh = lane >> 5;
    float a = 0.f;
#pragma unroll
    for (int kk = 0; kk < 32; kk++) {
        int k = kh * 32 + kk;
        a += sh3[sub][k] * Wc1[k * 32 + j];
    }
    a += __shfl_xor(a, 32);
    float contrib = (lane < 32) ? fmaxf(a + bc1[j], 0.0f) * Wc2[j] : 0.0f;
    contrib += __shfl_xor(contrib, 16);
    contrib += __shfl_xor(contrib, 8);
    contrib += __shfl_xor(contrib, 4);
    contrib += __shfl_xor(contrib, 2);
    contrib += __shfl_xor(contrib, 1);
    if (lane == 0) out[gid] = contrib + bc2[0];
}

extern "C" void kernel_launch(void* const* d_in, const int* in_sizes, int n_in,
                              void* d_out, int out_size, void* d_ws, size_t ws_size,
                              hipStream_t stream) {
    const float* x   = (const float*)d_in[0];
    const int*   ei  = (const int*)d_in[1];
    const int*   bat = (const int*)d_in[2];
    const float* W1l = (const float*)d_in[3];
    const float* b1  = (const float*)d_in[4];
    const float* W1r = (const float*)d_in[5];
    const float* W2l = (const float*)d_in[6];
    const float* b2  = (const float*)d_in[7];
    const float* W2r = (const float*)d_in[8];
    const float* W3l = (const float*)d_in[9];
    const float* b3  = (const float*)d_in[10];
    const float* W3r = (const float*)d_in[11];
    const float* Wc1 = (const float*)d_in[12];
    const float* bc1 = (const float*)d_in[13];
    const float* Wc2 = (const float*)d_in[14];
    const float* bc2 = (const float*)d_in[15];

    float* ws = (float*)d_ws;
    // ---- workspace layout (float offsets) ----
    int*    rowptr = (int*)(ws);                              // [0, 100352)
    int*    esrc   = (int*)(ws + 100352);                     // [100352, 1300480)
    float*  A      = ws + 1300480;                            // 16384
    float*  B      = ws + 1316864;                            // 16384  (A,B contiguous: 32768)
    unsigned short* pw2 = (unsigned short*)(ws + 1333504);    // 8192 bf16
    unsigned short* xb  = (unsigned short*)(ws + 1337600);    // N*8 bf16
    unsigned short* hb1 = (unsigned short*)(ws + 1737728);    // N*64 bf16 = 3.2M floats
    unsigned short* hb2 = (unsigned short*)(ws + 4937728);
    int*    ebuf   = (int*)(ws + 8137728);                    // 1200000
    int*    histm  = (int*)(ws + 9337728);                    // 98*392 = 38416 (transposed layout)
    int*    bstart = (int*)(ws + 9376144);                    // 393

    setup_kernel<<<649, 256, 0, stream>>>(x, xb, W2l, W2r, pw2, A, ei, histm);
    bucketC<<<EBLK, 512, 0, stream>>>(ei, histm, ebuf, bstart);
    bucketD_l1<<<NBUCK, 256, 0, stream>>>(ebuf, bstart, rowptr, esrc, xb, W1l, b1, W1r, hb1);

    agg_gemm<<<N_NODES / 16, 256, 0, stream>>>(hb1, rowptr, esrc, pw2, b2, hb2, bat, B);
    aggpool3<<<N_NODES / 4, 256, 0, stream>>>(hb2, rowptr, esrc, bat, A);

    head2_kernel<<<N_GRAPHS / 4, 256, 0, stream>>>(A, B, bat, W3l, b3, W3r, Wc1, bc1, Wc2, bc2,
                                                   (float*)d_out);
}